// Round 6
// baseline (137.183 us; speedup 1.0000x reference)
//
#include <hip/hip_runtime.h>
#include <hip/hip_bf16.h>
#include <math.h>

typedef _Float16 half2_t __attribute__((ext_vector_type(2)));
typedef _Float16 half4_t __attribute__((ext_vector_type(4)));
typedef _Float16 half8_t __attribute__((ext_vector_type(8)));
typedef float float4_t __attribute__((ext_vector_type(4)));

#define MFMA16(a,b,c) __builtin_amdgcn_mfma_f32_16x16x16f16((a),(b),(c),0,0,0)
#define MFMA32(a,b,c) __builtin_amdgcn_mfma_f32_16x16x32_f16((a),(b),(c),0,0,0)

static __device__ __forceinline__ half2_t cvt_pk(float a, float b) {
  return __builtin_bit_cast(half2_t, __builtin_amdgcn_cvt_pkrtz(a, b));
}

static constexpr int NTOK = 21952;   // 64 windows * 343 tokens
static constexpr int NREG = 5488;    // 343*16 elems per (which,w,h) region
static constexpr float LOG2E = 1.44269504088896340736f;

// region id for mask: cls bits = (sz==1)<<2 | (sy==3)<<1 | (sx==3)
__device__ __forceinline__ int rid_of(int cls, int n) {
  int z = n / 49, r = n - z*49, y = r / 7, x = r - y*7;
  int rs = (cls & 4) ? (z < 4 ? 1 : 2) : 0;
  int rh = (cls & 2) ? (y < 4 ? 1 : 2) : 0;
  int rw = (cls & 1) ? (x < 4 ? 1 : 2) : 0;
  return rs*9 + rh*3 + rw;
}

// ---------------- K0a: weight transposes (fp32->f16) ----------------
__global__ __launch_bounds__(256) void k_precomp(
    const float* __restrict__ qkv_w, const float* __restrict__ proj_w,
    const float* __restrict__ fc1_w, const float* __restrict__ fc2_w,
    _Float16* __restrict__ qkv_wT, _Float16* __restrict__ proj_wT,
    _Float16* __restrict__ fc1_wT, _Float16* __restrict__ fc2_wT)
{
  int i = blockIdx.x * 256 + threadIdx.x;
  if (i < 49152) { int n = i >> 7, k = i & 127; qkv_wT[i] = (_Float16)qkv_w[k*384 + n]; return; }
  i -= 49152;
  if (i < 16384) { int n = i >> 7, k = i & 127; proj_wT[i] = (_Float16)proj_w[k*128 + n]; return; }
  i -= 16384;
  if (i < 65536) { int n = i >> 7, k = i & 127; fc1_wT[i] = (_Float16)fc1_w[k*512 + n]; return; }
  i -= 65536;
  if (i < 65536) { int n = i >> 9, k = i & 511; fc2_wT[i] = (_Float16)fc2_w[k*128 + n]; }
}

// ---------------- K0b: combined bias+mask table (log2 domain) ----------------
// biasM[(cls*8+h)][q][k]: rpb*log2e where same-region, -30000 where masked or k>=343.
__global__ __launch_bounds__(256) void k_bias(
    const float* __restrict__ rpb, _Float16* __restrict__ biasM)
{
  int q  = blockIdx.x;            // 0..342
  int ch = blockIdx.y;            // cls*8 + h
  int cls = ch >> 3, h = ch & 7;
  int zq = q/49, rq_ = q - zq*49, yq = rq_/7, xq = rq_ - yq*7;
  int ridq = rid_of(cls, q);
  _Float16* dst = biasM + ((size_t)ch*343 + q)*352;
  for (int k = threadIdx.x; k < 352; k += 256) {
    _Float16 v = (_Float16)(-30000.f);
    if (k < 343) {
      int zk = k/49, rk_ = k - zk*49, yk = rk_/7, xk = rk_ - yk*7;
      if (rid_of(cls, k) == ridq) {
        int idx = 20*(yq - yk + 6) + 13*(zq - zk + 6) + (xq - xk + 6);
        v = (_Float16)(rpb[idx*8 + h] * LOG2E);
      }
    }
    dst[k] = v;
  }
}

// ---------------- QKV epilogue (scatter to per-(w,h) q/k/v regions) ----------------
__device__ __forceinline__ void qkv_store(int row, int col, float v,
    const float* __restrict__ bias, _Float16* __restrict__ outh)
{
  v += bias[col];
  int which = col >> 7;
  if (which == 0) v *= 0.25f;                 // SCALE = (C/NH)^-0.5
  int hh = (col >> 4) & 7, d = col & 15;
  int w = row / 343, n = row - w*343;
  size_t base = (size_t)((which*64 + w)*8 + hh)*NREG;
  if (which == 2) outh[base + d*343 + n] = (_Float16)v;   // V^T layout
  else            outh[base + n*16  + d] = (_Float16)v;
}

// ---------------- K1: fused LN1(+roll+partition) + QKV GEMM ----------------
__global__ __launch_bounds__(384) void k_qkv(
    const float* __restrict__ x, const float* __restrict__ g1, const float* __restrict__ b1,
    const _Float16* __restrict__ qkv_wT, const float* __restrict__ qkv_b,
    _Float16* __restrict__ qkvb)
{
  __shared__ _Float16 A[32][136];   // +8 pad: 272B row stride -> 2-way bank alias (free)
  int mt = blockIdx.x;
  int tid = threadIdx.x, wid = tid >> 6, lane = tid & 63;
  for (int r = wid; r < 32; r += 6) {
    int row = mt*32 + r;
    int w = row / 343, n = row - w*343;
    int b = w >> 5, widx = w & 31;
    int sz = widx >> 4, sy = (widx >> 2) & 3, sx = widx & 3;
    int z = n / 49, rem = n - z*49, y = rem / 7, xx = rem - y*7;
    int gs = sz*7 + z + 3;  if (gs >= 14) gs -= 14;
    int gh = sy*7 + y + 3;  if (gh >= 28) gh -= 28;
    int gw = sx*7 + xx + 3; if (gw >= 28) gw -= 28;
    int gt = b*10976 + (gs*28 + gh)*28 + gw;
    const float* xr = x + (size_t)gt*128;
    float2 v = *(const float2*)(xr + lane*2);
    float s = v.x + v.y, sq = v.x*v.x + v.y*v.y;
    #pragma unroll
    for (int o = 1; o < 64; o <<= 1) { s += __shfl_xor(s, o); sq += __shfl_xor(sq, o); }
    float mu = s * 0.0078125f;
    float rstd = rsqrtf(sq*0.0078125f - mu*mu + 1e-5f);
    int c = lane*2;
    half2_t hv = { (_Float16)((v.x-mu)*rstd*g1[c]   + b1[c]),
                   (_Float16)((v.y-mu)*rstd*g1[c+1] + b1[c+1]) };
    *(half2_t*)&A[r][c] = hv;
  }
  __syncthreads();
  int lo = lane & 15, grp = lane >> 4;
  const _Float16* bp = qkv_wT + (size_t)(wid*64 + lo)*128 + grp*8;
  float4_t a00={0,0,0,0}, a01={0,0,0,0}, a02={0,0,0,0}, a03={0,0,0,0};
  float4_t a10={0,0,0,0}, a11={0,0,0,0}, a12={0,0,0,0}, a13={0,0,0,0};
  #pragma unroll
  for (int kk = 0; kk < 128; kk += 32) {
    half8_t f0 = *(const half8_t*)&A[lo][kk + grp*8];
    half8_t f1 = *(const half8_t*)&A[16 + lo][kk + grp*8];
    half8_t b0 = *(const half8_t*)(bp + kk);
    half8_t b1 = *(const half8_t*)(bp + kk + (size_t)16*128);
    half8_t b2 = *(const half8_t*)(bp + kk + (size_t)32*128);
    half8_t b3 = *(const half8_t*)(bp + kk + (size_t)48*128);
    a00 = MFMA32(f0, b0, a00);  a01 = MFMA32(f0, b1, a01);
    a02 = MFMA32(f0, b2, a02);  a03 = MFMA32(f0, b3, a03);
    a10 = MFMA32(f1, b0, a10);  a11 = MFMA32(f1, b1, a11);
    a12 = MFMA32(f1, b2, a12);  a13 = MFMA32(f1, b3, a13);
  }
  int row0 = mt*32 + grp*4;
  int colb = wid*64 + lo;
  #pragma unroll
  for (int r = 0; r < 4; ++r) {
    qkv_store(row0+r,    colb,    a00[r], qkv_b, qkvb);
    qkv_store(row0+r,    colb+16, a01[r], qkv_b, qkvb);
    qkv_store(row0+r,    colb+32, a02[r], qkv_b, qkvb);
    qkv_store(row0+r,    colb+48, a03[r], qkv_b, qkvb);
    qkv_store(row0+16+r, colb,    a10[r], qkv_b, qkvb);
    qkv_store(row0+16+r, colb+16, a11[r], qkv_b, qkvb);
    qkv_store(row0+16+r, colb+32, a12[r], qkv_b, qkvb);
    qkv_store(row0+16+r, colb+48, a13[r], qkv_b, qkvb);
  }
}

// ---------------- K3: windowed attention ----------------
// Combined bias+mask table (log2-domain, -30000 = masked/pad) -> inner loop is
// just fma+exp2+add per element. Output written directly in token order.
__global__ __launch_bounds__(512) void k_attn(
    const _Float16* __restrict__ qkv, const _Float16* __restrict__ biasM,
    _Float16* __restrict__ obuf)
{
  __shared__ _Float16 Klds[352][24];
  __shared__ _Float16 VTlds[16][360];
  int bx = blockIdx.x;
  int w = bx >> 3, h = bx & 7;
  int b = w >> 5, widx = w & 31;
  int sz = widx >> 4, sy = (widx >> 2) & 3, sx = widx & 3;
  int cls = (sz << 2) | (sy == 3 ? 2 : 0) | (sx == 3 ? 1 : 0);
  int tid = threadIdx.x;
  const _Float16* qp  = qkv + (size_t)(w*8 + h) * NREG;
  const _Float16* kp  = qp + (size_t)512  * NREG;
  const _Float16* vtp = qp + (size_t)1024 * NREG;   // [d][n]
  for (int c = tid; c < 704; c += 512) {
    int n = c >> 1, d0 = (c & 1) * 8;
    half8_t kv = {};
    if (n < 343) kv = *(const half8_t*)(kp + n*16 + d0);
    *(half8_t*)&Klds[n][d0] = kv;
  }
  for (int c = tid; c < 704; c += 512) {
    int d = c / 44, n0 = (c - d*44) * 8;
    half8_t vv = {};
    if (n0 + 8 <= 343) vv = *(const half8_t*)(vtp + d*343 + n0);
    else { for (int j = 0; j < 8; ++j) vv[j] = (n0 + j < 343) ? vtp[d*343 + n0 + j] : (_Float16)0.f; }
    *(half8_t*)&VTlds[d][n0] = vv;
  }
  __syncthreads();
  int lane = tid & 63, lo = lane & 15, grp = lane >> 4;
  int wid = tid >> 6;
  const _Float16* btab = biasM + (size_t)(cls*8 + h)*343*352;
  for (int qt = wid; qt < 22; qt += 8) {
    int q  = qt*16 + lo;
    int qv = q < 343 ? q : 342;
    half4_t qf = *(const half4_t*)(qp + (size_t)qv*16 + grp*4);
    const _Float16* bp = btab + (size_t)qv*352;
    half4_t barr0[11], barr1[11];
    #pragma unroll
    for (int kt = 0; kt < 11; ++kt) {
      barr0[kt] = *(const half4_t*)(bp + kt*32 + grp*4);
      barr1[kt] = *(const half4_t*)(bp + kt*32 + 16 + grp*4);
    }
    float lsum = 0.f;
    float4_t acc = {0.f, 0.f, 0.f, 0.f};
    #pragma unroll
    for (int kt = 0; kt < 11; ++kt) {
      int kb = kt*32;
      half4_t ka0 = *(const half4_t*)&Klds[kb + lo][grp*4];
      half4_t ka1 = *(const half4_t*)&Klds[kb + 16 + lo][grp*4];
      float4_t zero = {0.f, 0.f, 0.f, 0.f};
      float4_t s0 = MFMA16(ka0, qf, zero);
      float4_t s1 = MFMA16(ka1, qf, zero);
      float p[8];
      #pragma unroll
      for (int i = 0; i < 8; ++i) {
        float sv = (i < 4) ? s0[i] : s1[i-4];
        float bb = (float)((i < 4) ? barr0[kt][i] : barr1[kt][i-4]);
        float e = exp2f(fmaf(sv, LOG2E, bb));
        p[i] = e;
        lsum += e;
      }
      half2_t pk01 = cvt_pk(p[0], p[1]);
      half2_t pk23 = cvt_pk(p[2], p[3]);
      half2_t pk45 = cvt_pk(p[4], p[5]);
      half2_t pk67 = cvt_pk(p[6], p[7]);
      half4_t pb0 = __builtin_shufflevector(pk01, pk23, 0, 1, 2, 3);
      half4_t pb1 = __builtin_shufflevector(pk45, pk67, 0, 1, 2, 3);
      half4_t va0 = *(const half4_t*)&VTlds[lo][kb + grp*4];
      half4_t va1 = *(const half4_t*)&VTlds[lo][kb + 16 + grp*4];
      acc = MFMA16(va0, pb0, acc);
      acc = MFMA16(va1, pb1, acc);
    }
    lsum += __shfl_xor(lsum, 16);
    lsum += __shfl_xor(lsum, 32);
    if (q < 343) {
      // token-order output row (roll + window-reverse analytic)
      int z = q/49, rem = q - z*49, y = rem/7, xx = rem - y*7;
      int gs = sz*7 + z + 3;  if (gs >= 14) gs -= 14;
      int gh = sy*7 + y + 3;  if (gh >= 28) gh -= 28;
      int gw = sx*7 + xx + 3; if (gw >= 28) gw -= 28;
      int gt = b*10976 + (gs*28 + gh)*28 + gw;
      float rl = 1.f / lsum;
      half4_t o4 = { (_Float16)(acc[0]*rl), (_Float16)(acc[1]*rl),
                     (_Float16)(acc[2]*rl), (_Float16)(acc[3]*rl) };
      *(half4_t*)(obuf + (size_t)gt*128 + h*16 + grp*4) = o4;
    }
  }
}

// ---------------- K4: fused proj + residual + LN2 + FC1 + GELU ----------------
__global__ __launch_bounds__(512) void k_mlp(
    const _Float16* __restrict__ obuf, const _Float16* __restrict__ proj_wT,
    const float* __restrict__ proj_b, const float* __restrict__ x,
    const float* __restrict__ g2, const float* __restrict__ b2,
    const _Float16* __restrict__ fc1_wT, const float* __restrict__ fc1_b,
    float* __restrict__ x2, _Float16* __restrict__ hid)
{
  __shared__ _Float16 P[32][136];   // attn-out rows; later reused as LN'd FC1 A-tile
  __shared__ float    X2[32][132];
  int mt = blockIdx.x;
  int tid = threadIdx.x, wid = tid >> 6, lane = tid & 63, lo = lane & 15, grp = lane >> 4;
  // phase 0: copy attention-output rows (token order, contiguous) into LDS
  for (int r = wid; r < 32; r += 8) {
    int row = mt*32 + r;
    half2_t v = *(const half2_t*)(obuf + (size_t)row*128 + lane*2);
    *(half2_t*)&P[r][lane*2] = v;
  }
  __syncthreads();
  // phase 1: proj GEMM, wave -> 16-col stripe; +bias +shortcut -> x2 (global+LDS)
  {
    const _Float16* bp = proj_wT + (size_t)(wid*16 + lo)*128 + grp*8;
    float4_t a0={0,0,0,0}, a1={0,0,0,0};
    #pragma unroll
    for (int kk = 0; kk < 128; kk += 32) {
      half8_t f0 = *(const half8_t*)&P[lo][kk + grp*8];
      half8_t f1 = *(const half8_t*)&P[16 + lo][kk + grp*8];
      half8_t b0 = *(const half8_t*)(bp + kk);
      a0 = MFMA32(f0, b0, a0);
      a1 = MFMA32(f1, b0, a1);
    }
    int colb = wid*16 + lo;
    float bb = proj_b[colb];
    #pragma unroll
    for (int r = 0; r < 4; ++r) {
      int r0 = grp*4 + r;
      int row0 = mt*32 + r0, row1 = row0 + 16;
      float w0 = x[(size_t)row0*128 + colb] + a0[r] + bb;
      float w1 = x[(size_t)row1*128 + colb] + a1[r] + bb;
      x2[(size_t)row0*128 + colb] = w0;  X2[r0][colb]    = w0;
      x2[(size_t)row1*128 + colb] = w1;  X2[r0+16][colb] = w1;
    }
  }
  __syncthreads();
  // phase 2: LN2 from LDS -> P (f16 A-tile)
  for (int r = wid; r < 32; r += 8) {
    float2 v = { X2[r][lane*2], X2[r][lane*2 + 1] };
    float s = v.x + v.y, sq = v.x*v.x + v.y*v.y;
    #pragma unroll
    for (int o = 1; o < 64; o <<= 1) { s += __shfl_xor(s, o); sq += __shfl_xor(sq, o); }
    float mu = s * 0.0078125f;
    float rstd = rsqrtf(sq*0.0078125f - mu*mu + 1e-5f);
    int c = lane*2;
    half2_t hv = { (_Float16)((v.x-mu)*rstd*g2[c]   + b2[c]),
                   (_Float16)((v.y-mu)*rstd*g2[c+1] + b2[c+1]) };
    *(half2_t*)&P[r][c] = hv;
  }
  __syncthreads();
  // phase 3: FC1 GEMM, wave -> 64-col stripe; GELU -> hid (f16)
  {
    const _Float16* bp = fc1_wT + (size_t)(wid*64 + lo)*128 + grp*8;
    float4_t a00={0,0,0,0}, a01={0,0,0,0}, a02={0,0,0,0}, a03={0,0,0,0};
    float4_t a10={0,0,0,0}, a11={0,0,0,0}, a12={0,0,0,0}, a13={0,0,0,0};
    #pragma unroll
    for (int kk = 0; kk < 128; kk += 32) {
      half8_t f0 = *(const half8_t*)&P[lo][kk + grp*8];
      half8_t f1 = *(const half8_t*)&P[16 + lo][kk + grp*8];
      half8_t b0 = *(const half8_t*)(bp + kk);
      half8_t b1 = *(const half8_t*)(bp + kk + (size_t)16*128);
      half8_t b2 = *(const half8_t*)(bp + kk + (size_t)32*128);
      half8_t b3 = *(const half8_t*)(bp + kk + (size_t)48*128);
      a00 = MFMA32(f0, b0, a00);  a01 = MFMA32(f0, b1, a01);
      a02 = MFMA32(f0, b2, a02);  a03 = MFMA32(f0, b3, a03);
      a10 = MFMA32(f1, b0, a10);  a11 = MFMA32(f1, b1, a11);
      a12 = MFMA32(f1, b2, a12);  a13 = MFMA32(f1, b3, a13);
    }
    int row0 = mt*32 + grp*4;
    int colb = wid*64 + lo;
    #pragma unroll
    for (int r = 0; r < 4; ++r) {
      float vv[8] = { a00[r], a01[r], a02[r], a03[r], a10[r], a11[r], a12[r], a13[r] };
      #pragma unroll
      for (int j = 0; j < 8; ++j) {
        int rr  = row0 + r + (j >= 4 ? 16 : 0);
        int col = colb + (j & 3)*16;
        float v = vv[j] + fc1_b[col];
        float g = 0.5f * v * (1.0f + erff(v * 0.70710678118654752f));
        hid[(size_t)rr*512 + col] = (_Float16)g;
      }
    }
  }
}

// ---------------- K5: FC2 + bias + residual -> out ----------------
__global__ __launch_bounds__(256) void k_fc2(
    const _Float16* __restrict__ hid, const _Float16* __restrict__ fc2_wT,
    const float* __restrict__ fc2_b, const float* __restrict__ x2,
    float* __restrict__ out)
{
  int gw = blockIdx.x*4 + (threadIdx.x >> 6);
  int nb = gw / 1372;
  int mt = gw - nb*1372;
  int lane = threadIdx.x & 63, lo = lane & 15, grp = lane >> 4;
  const _Float16* ap = hid + (size_t)(mt*16 + lo)*512 + grp*8;
  const _Float16* bp = fc2_wT + (size_t)(nb*64 + lo)*512 + grp*8;
  float4_t acc0 = {0,0,0,0}, acc1 = {0,0,0,0}, acc2 = {0,0,0,0}, acc3 = {0,0,0,0};
  for (int kk = 0; kk < 512; kk += 32) {
    half8_t a  = *(const half8_t*)(ap + kk);
    half8_t b0 = *(const half8_t*)(bp + kk);
    half8_t b1 = *(const half8_t*)(bp + kk + (size_t)16*512);
    half8_t b2 = *(const half8_t*)(bp + kk + (size_t)32*512);
    half8_t b3 = *(const half8_t*)(bp + kk + (size_t)48*512);
    acc0 = MFMA32(a, b0, acc0);
    acc1 = MFMA32(a, b1, acc1);
    acc2 = MFMA32(a, b2, acc2);
    acc3 = MFMA32(a, b3, acc3);
  }
  int rowb = mt*16 + grp*4;
  int colb = nb*64 + lo;
  #pragma unroll
  for (int r = 0; r < 4; ++r) {
    int row = rowb + r;
    out[(size_t)row*128 + colb]      = x2[(size_t)row*128 + colb]      + acc0[r] + fc2_b[colb];
    out[(size_t)row*128 + colb + 16] = x2[(size_t)row*128 + colb + 16] + acc1[r] + fc2_b[colb+16];
    out[(size_t)row*128 + colb + 32] = x2[(size_t)row*128 + colb + 32] + acc2[r] + fc2_b[colb+32];
    out[(size_t)row*128 + colb + 48] = x2[(size_t)row*128 + colb + 48] + acc3[r] + fc2_b[colb+48];
  }
}

extern "C" void kernel_launch(void* const* d_in, const int* in_sizes, int n_in,
                              void* d_out, int out_size, void* d_ws, size_t ws_size,
                              hipStream_t stream)
{
  const float* x      = (const float*)d_in[0];
  // d_in[1] mask_matrix, d_in[15] rel_index: reproduced analytically in-kernel
  const float* g1     = (const float*)d_in[2];
  const float* b1     = (const float*)d_in[3];
  const float* qkv_w  = (const float*)d_in[4];
  const float* qkv_b  = (const float*)d_in[5];
  const float* rpb    = (const float*)d_in[6];
  const float* proj_w = (const float*)d_in[7];
  const float* proj_b = (const float*)d_in[8];
  const float* g2     = (const float*)d_in[9];
  const float* b2     = (const float*)d_in[10];
  const float* fc1_w  = (const float*)d_in[11];
  const float* fc1_b  = (const float*)d_in[12];
  const float* fc2_w  = (const float*)d_in[13];
  const float* fc2_b  = (const float*)d_in[14];
  char* ws = (char*)d_ws;
  size_t o = 0;
  auto alloc = [&](size_t bytes) { size_t r = o; o += (bytes + 255) & ~size_t(255); return r; };
  size_t oOB  = alloc((size_t)NTOK*128*2);       // obuf (attn out, token order)
  size_t oX2  = alloc((size_t)NTOK*128*4);       // x2 = shortcut + proj out, fp32
  size_t oU   = alloc((size_t)NTOK*512*2);       // qkvb then hid (sequentially dead, aliased)
  size_t oWQ  = alloc(49152*2);
  size_t oWP  = alloc(16384*2);
  size_t oW1  = alloc(65536*2);
  size_t oW2  = alloc(65536*2);
  size_t oBMC = alloc((size_t)64*343*352*2);     // combined bias+mask, f16 log2-domain
  (void)ws_size; (void)in_sizes; (void)n_in; (void)out_size;
  _Float16* obuf   = (_Float16*)(ws + oOB);
  float*    x2     = (float*)(ws + oX2);
  _Float16* qkvb   = (_Float16*)(ws + oU);
  _Float16* hid    = (_Float16*)(ws + oU);
  _Float16* qkv_wT = (_Float16*)(ws + oWQ);
  _Float16* proj_wT= (_Float16*)(ws + oWP);
  _Float16* fc1_wT = (_Float16*)(ws + oW1);
  _Float16* fc2_wT = (_Float16*)(ws + oW2);
  _Float16* biasM  = (_Float16*)(ws + oBMC);
  float*    out    = (float*)d_out;

  k_precomp<<<768, 256, 0, stream>>>(qkv_w, proj_w, fc1_w, fc2_w,
                                     qkv_wT, proj_wT, fc1_wT, fc2_wT);
  k_bias<<<dim3(343, 64), 256, 0, stream>>>(rpb, biasM);
  k_qkv<<<686, 384, 0, stream>>>(x, g1, b1, qkv_wT, qkv_b, qkvb);
  k_attn<<<512, 512, 0, stream>>>(qkvb, biasM, obuf);
  k_mlp<<<686, 512, 0, stream>>>(obuf, proj_wT, proj_b, x, g2, b2,
                                 fc1_wT, fc1_b, x2, hid);
  k_fc2<<<686, 256, 0, stream>>>(hid, fc2_wT, fc2_b, x2, out);
}

// Round 7
// 126.882 us; speedup vs baseline: 1.0812x; 1.0812x over previous
//
#include <hip/hip_runtime.h>
#include <hip/hip_bf16.h>
#include <math.h>

typedef _Float16 half2_t __attribute__((ext_vector_type(2)));
typedef _Float16 half4_t __attribute__((ext_vector_type(4)));
typedef _Float16 half8_t __attribute__((ext_vector_type(8)));
typedef float float4_t __attribute__((ext_vector_type(4)));

#define MFMA16(a,b,c) __builtin_amdgcn_mfma_f32_16x16x16f16((a),(b),(c),0,0,0)
#define MFMA32(a,b,c) __builtin_amdgcn_mfma_f32_16x16x32_f16((a),(b),(c),0,0,0)

static __device__ __forceinline__ half2_t cvt_pk(float a, float b) {
  return __builtin_bit_cast(half2_t, __builtin_amdgcn_cvt_pkrtz(a, b));
}

static constexpr int NTOK = 21952;   // 64 windows * 343 tokens
static constexpr int NREG = 5488;    // 343*16 elems per (which,w,h) region
static constexpr float LOG2E = 1.44269504088896340736f;

// region id for mask: cls bits = (sz==1)<<2 | (sy==3)<<1 | (sx==3)
__device__ __forceinline__ int rid_of(int cls, int n) {
  int z = n / 49, r = n - z*49, y = r / 7, x = r - y*7;
  int rs = (cls & 4) ? (z < 4 ? 1 : 2) : 0;
  int rh = (cls & 2) ? (y < 4 ? 1 : 2) : 0;
  int rw = (cls & 1) ? (x < 4 ? 1 : 2) : 0;
  return rs*9 + rh*3 + rw;
}

// ---------------- K0: weight transposes + bias table (log2e) + mask bitmasks ----------------
__global__ __launch_bounds__(256) void k_precomp(
    const float* __restrict__ qkv_w, const float* __restrict__ proj_w,
    const float* __restrict__ fc1_w, const float* __restrict__ fc2_w,
    const float* __restrict__ rpb,
    _Float16* __restrict__ qkv_wT, _Float16* __restrict__ proj_wT,
    _Float16* __restrict__ fc1_wT, _Float16* __restrict__ fc2_wT,
    _Float16* __restrict__ biasT, unsigned* __restrict__ bmask)
{
  int i = blockIdx.x * 256 + threadIdx.x;
  if (i < 49152) { int n = i >> 7, k = i & 127; qkv_wT[i] = (_Float16)qkv_w[k*384 + n]; return; }
  i -= 49152;
  if (i < 16384) { int n = i >> 7, k = i & 127; proj_wT[i] = (_Float16)proj_w[k*128 + n]; return; }
  i -= 16384;
  if (i < 65536) { int n = i >> 7, k = i & 127; fc1_wT[i] = (_Float16)fc1_w[k*512 + n]; return; }
  i -= 65536;
  if (i < 65536) { int n = i >> 9, k = i & 511; fc2_wT[i] = (_Float16)fc2_w[k*128 + n]; return; }
  i -= 65536;
  if (i < 8*343*352) {
    int h = i / (343*352); int r = i - h*343*352; int q = r / 352; int k = r - q*352;
    _Float16 v;
    if (k >= 343) v = (_Float16)(-30000.f);          // exp2 -> 0
    else {
      int zq = q/49, rq_ = q - zq*49, yq = rq_/7, xq = rq_ - yq*7;
      int zk = k/49, rk_ = k - zk*49, yk = rk_/7, xk = rk_ - yk*7;
      int idx = 20*(yq - yk + 6) + 13*(zq - zk + 6) + (xq - xk + 6);
      v = (_Float16)(rpb[idx*8 + h] * LOG2E);        // log2-domain bias
    }
    biasT[i] = v;
    return;
  }
  i -= 8*343*352;
  if (i < 8*343*11) {
    int cls = i / (343*11); int r = i - cls*343*11; int q = r / 11; int kt = r - q*11;
    int rq = rid_of(cls, q);
    unsigned wbits = 0u;
    for (int j = 0; j < 32; ++j) {
      int k = kt*32 + j;
      if (k < 343 && rid_of(cls, k) == rq) wbits |= (1u << j);
    }
    bmask[i] = wbits;
  }
}

// ---------------- QKV epilogue (scatter to per-(w,h) q/k/v regions) ----------------
__device__ __forceinline__ void qkv_store(int row, int col, float v,
    const float* __restrict__ bias, _Float16* __restrict__ outh)
{
  v += bias[col];
  int which = col >> 7;
  if (which == 0) v *= 0.25f;                 // SCALE = (C/NH)^-0.5
  int hh = (col >> 4) & 7, d = col & 15;
  int w = row / 343, n = row - w*343;
  size_t base = (size_t)((which*64 + w)*8 + hh)*NREG;
  if (which == 2) outh[base + d*343 + n] = (_Float16)v;   // V^T layout
  else            outh[base + n*16  + d] = (_Float16)v;
}

// ---------------- K1: fused LN1(+roll+partition) + QKV GEMM ----------------
__global__ __launch_bounds__(384) void k_qkv(
    const float* __restrict__ x, const float* __restrict__ g1, const float* __restrict__ b1,
    const _Float16* __restrict__ qkv_wT, const float* __restrict__ qkv_b,
    _Float16* __restrict__ qkvb)
{
  __shared__ _Float16 A[32][136];   // +8 pad: 272B row stride -> 2-way bank alias (free)
  int mt = blockIdx.x;
  int tid = threadIdx.x, wid = tid >> 6, lane = tid & 63;
  for (int r = wid; r < 32; r += 6) {
    int row = mt*32 + r;
    int w = row / 343, n = row - w*343;
    int b = w >> 5, widx = w & 31;
    int sz = widx >> 4, sy = (widx >> 2) & 3, sx = widx & 3;
    int z = n / 49, rem = n - z*49, y = rem / 7, xx = rem - y*7;
    int gs = sz*7 + z + 3;  if (gs >= 14) gs -= 14;
    int gh = sy*7 + y + 3;  if (gh >= 28) gh -= 28;
    int gw = sx*7 + xx + 3; if (gw >= 28) gw -= 28;
    int gt = b*10976 + (gs*28 + gh)*28 + gw;
    const float* xr = x + (size_t)gt*128;
    float2 v = *(const float2*)(xr + lane*2);
    float s = v.x + v.y, sq = v.x*v.x + v.y*v.y;
    #pragma unroll
    for (int o = 1; o < 64; o <<= 1) { s += __shfl_xor(s, o); sq += __shfl_xor(sq, o); }
    float mu = s * 0.0078125f;
    float rstd = rsqrtf(sq*0.0078125f - mu*mu + 1e-5f);
    int c = lane*2;
    half2_t hv = { (_Float16)((v.x-mu)*rstd*g1[c]   + b1[c]),
                   (_Float16)((v.y-mu)*rstd*g1[c+1] + b1[c+1]) };
    *(half2_t*)&A[r][c] = hv;
  }
  __syncthreads();
  int lo = lane & 15, grp = lane >> 4;
  const _Float16* bp = qkv_wT + (size_t)(wid*64 + lo)*128 + grp*8;
  float4_t a00={0,0,0,0}, a01={0,0,0,0}, a02={0,0,0,0}, a03={0,0,0,0};
  float4_t a10={0,0,0,0}, a11={0,0,0,0}, a12={0,0,0,0}, a13={0,0,0,0};
  #pragma unroll
  for (int kk = 0; kk < 128; kk += 32) {
    half8_t f0 = *(const half8_t*)&A[lo][kk + grp*8];
    half8_t f1 = *(const half8_t*)&A[16 + lo][kk + grp*8];
    half8_t b0 = *(const half8_t*)(bp + kk);
    half8_t b1 = *(const half8_t*)(bp + kk + (size_t)16*128);
    half8_t b2 = *(const half8_t*)(bp + kk + (size_t)32*128);
    half8_t b3 = *(const half8_t*)(bp + kk + (size_t)48*128);
    a00 = MFMA32(f0, b0, a00);  a01 = MFMA32(f0, b1, a01);
    a02 = MFMA32(f0, b2, a02);  a03 = MFMA32(f0, b3, a03);
    a10 = MFMA32(f1, b0, a10);  a11 = MFMA32(f1, b1, a11);
    a12 = MFMA32(f1, b2, a12);  a13 = MFMA32(f1, b3, a13);
  }
  int row0 = mt*32 + grp*4;
  int colb = wid*64 + lo;
  #pragma unroll
  for (int r = 0; r < 4; ++r) {
    qkv_store(row0+r,    colb,    a00[r], qkv_b, qkvb);
    qkv_store(row0+r,    colb+16, a01[r], qkv_b, qkvb);
    qkv_store(row0+r,    colb+32, a02[r], qkv_b, qkvb);
    qkv_store(row0+r,    colb+48, a03[r], qkv_b, qkvb);
    qkv_store(row0+16+r, colb,    a10[r], qkv_b, qkvb);
    qkv_store(row0+16+r, colb+16, a11[r], qkv_b, qkvb);
    qkv_store(row0+16+r, colb+32, a12[r], qkv_b, qkvb);
    qkv_store(row0+16+r, colb+48, a13[r], qkv_b, qkvb);
  }
}

// ---------------- K3: windowed attention (R5 core + token-order output) ----------------
__global__ __launch_bounds__(512) void k_attn(
    const _Float16* __restrict__ qkv, const _Float16* __restrict__ biasT,
    const unsigned* __restrict__ bmask, _Float16* __restrict__ obuf)
{
  __shared__ _Float16 Klds[352][24];
  __shared__ _Float16 VTlds[16][360];
  int bx = blockIdx.x;
  int w = bx >> 3, h = bx & 7;
  int b = w >> 5, widx = w & 31;
  int sz = widx >> 4, sy = (widx >> 2) & 3, sx = widx & 3;
  int cls = (sz << 2) | (sy == 3 ? 2 : 0) | (sx == 3 ? 1 : 0);
  int tid = threadIdx.x;
  const _Float16* qp  = qkv + (size_t)(w*8 + h) * NREG;
  const _Float16* kp  = qp + (size_t)512  * NREG;
  const _Float16* vtp = qp + (size_t)1024 * NREG;   // [d][n]
  for (int c = tid; c < 704; c += 512) {
    int n = c >> 1, d0 = (c & 1) * 8;
    half8_t kv = {};
    if (n < 343) kv = *(const half8_t*)(kp + n*16 + d0);
    *(half8_t*)&Klds[n][d0] = kv;
  }
  for (int c = tid; c < 704; c += 512) {
    int d = c / 44, n0 = (c - d*44) * 8;
    half8_t vv = {};
    if (n0 + 8 <= 343) vv = *(const half8_t*)(vtp + d*343 + n0);
    else { for (int j = 0; j < 8; ++j) vv[j] = (n0 + j < 343) ? vtp[d*343 + n0 + j] : (_Float16)0.f; }
    *(half8_t*)&VTlds[d][n0] = vv;
  }
  __syncthreads();
  int lane = tid & 63, lo = lane & 15, grp = lane >> 4;
  int wid = tid >> 6;
  for (int qt = wid; qt < 22; qt += 8) {
    int q  = qt*16 + lo;
    int qv = q < 343 ? q : 342;
    half4_t qf = *(const half4_t*)(qp + (size_t)qv*16 + grp*4);
    const _Float16* bp  = biasT + (size_t)(h*343 + qv)*352;
    const unsigned* bmp = bmask + (size_t)(cls*343 + qv)*11;
    half4_t barr0[11], barr1[11];
    unsigned bmarr[11];
    #pragma unroll
    for (int kt = 0; kt < 11; ++kt) {
      barr0[kt] = *(const half4_t*)(bp + kt*32 + grp*4);
      barr1[kt] = *(const half4_t*)(bp + kt*32 + 16 + grp*4);
      bmarr[kt] = bmp[kt];
    }
    float lsum = 0.f;
    float4_t acc = {0.f, 0.f, 0.f, 0.f};
    #pragma unroll
    for (int kt = 0; kt < 11; ++kt) {
      int kb = kt*32;
      half4_t ka0 = *(const half4_t*)&Klds[kb + lo][grp*4];
      half4_t ka1 = *(const half4_t*)&Klds[kb + 16 + lo][grp*4];
      float4_t zero = {0.f, 0.f, 0.f, 0.f};
      float4_t s0 = MFMA16(ka0, qf, zero);
      float4_t s1 = MFMA16(ka1, qf, zero);
      unsigned bmw = bmarr[kt];
      float p[8];
      #pragma unroll
      for (int i = 0; i < 8; ++i) {
        float sv = (i < 4) ? s0[i] : s1[i-4];
        float bb = (float)((i < 4) ? barr0[kt][i] : barr1[kt][i-4]);
        float e = exp2f(fmaf(sv, LOG2E, bb));
        unsigned bit = (bmw >> ((i >> 2)*16 + grp*4 + (i & 3))) & 1u;
        p[i] = bit ? e : 0.f;
        lsum += p[i];
      }
      half2_t pk01 = cvt_pk(p[0], p[1]);
      half2_t pk23 = cvt_pk(p[2], p[3]);
      half2_t pk45 = cvt_pk(p[4], p[5]);
      half2_t pk67 = cvt_pk(p[6], p[7]);
      half4_t pb0 = __builtin_shufflevector(pk01, pk23, 0, 1, 2, 3);
      half4_t pb1 = __builtin_shufflevector(pk45, pk67, 0, 1, 2, 3);
      half4_t va0 = *(const half4_t*)&VTlds[lo][kb + grp*4];
      half4_t va1 = *(const half4_t*)&VTlds[lo][kb + 16 + grp*4];
      acc = MFMA16(va0, pb0, acc);
      acc = MFMA16(va1, pb1, acc);
    }
    lsum += __shfl_xor(lsum, 16);
    lsum += __shfl_xor(lsum, 32);
    if (q < 343) {
      // token-order output row (roll + window-reverse analytic)
      int z = q/49, rem = q - z*49, y = rem/7, xx = rem - y*7;
      int gs = sz*7 + z + 3;  if (gs >= 14) gs -= 14;
      int gh = sy*7 + y + 3;  if (gh >= 28) gh -= 28;
      int gw = sx*7 + xx + 3; if (gw >= 28) gw -= 28;
      int gt = b*10976 + (gs*28 + gh)*28 + gw;
      float rl = 1.f / lsum;
      half4_t o4 = { (_Float16)(acc[0]*rl), (_Float16)(acc[1]*rl),
                     (_Float16)(acc[2]*rl), (_Float16)(acc[3]*rl) };
      *(half4_t*)(obuf + (size_t)gt*128 + h*16 + grp*4) = o4;
    }
  }
}

// ---------------- K4: fused proj + residual + LN2 + FC1 + GELU ----------------
__global__ __launch_bounds__(512) void k_mlp(
    const _Float16* __restrict__ obuf, const _Float16* __restrict__ proj_wT,
    const float* __restrict__ proj_b, const float* __restrict__ x,
    const float* __restrict__ g2, const float* __restrict__ b2,
    const _Float16* __restrict__ fc1_wT, const float* __restrict__ fc1_b,
    float* __restrict__ x2, _Float16* __restrict__ hid)
{
  __shared__ _Float16 P[32][136];   // attn-out rows; later reused as LN'd FC1 A-tile
  __shared__ float    X2[32][132];
  int mt = blockIdx.x;
  int tid = threadIdx.x, wid = tid >> 6, lane = tid & 63, lo = lane & 15, grp = lane >> 4;
  // phase 0: copy attention-output rows (token order, contiguous) into LDS
  for (int r = wid; r < 32; r += 8) {
    int row = mt*32 + r;
    half2_t v = *(const half2_t*)(obuf + (size_t)row*128 + lane*2);
    *(half2_t*)&P[r][lane*2] = v;
  }
  __syncthreads();
  // phase 1: proj GEMM, wave -> 16-col stripe; +bias +shortcut -> x2 (global+LDS)
  {
    const _Float16* bp = proj_wT + (size_t)(wid*16 + lo)*128 + grp*8;
    float4_t a0={0,0,0,0}, a1={0,0,0,0};
    #pragma unroll
    for (int kk = 0; kk < 128; kk += 32) {
      half8_t f0 = *(const half8_t*)&P[lo][kk + grp*8];
      half8_t f1 = *(const half8_t*)&P[16 + lo][kk + grp*8];
      half8_t b0 = *(const half8_t*)(bp + kk);
      a0 = MFMA32(f0, b0, a0);
      a1 = MFMA32(f1, b0, a1);
    }
    int colb = wid*16 + lo;
    float bb = proj_b[colb];
    #pragma unroll
    for (int r = 0; r < 4; ++r) {
      int r0 = grp*4 + r;
      int row0 = mt*32 + r0, row1 = row0 + 16;
      float w0 = x[(size_t)row0*128 + colb] + a0[r] + bb;
      float w1 = x[(size_t)row1*128 + colb] + a1[r] + bb;
      x2[(size_t)row0*128 + colb] = w0;  X2[r0][colb]    = w0;
      x2[(size_t)row1*128 + colb] = w1;  X2[r0+16][colb] = w1;
    }
  }
  __syncthreads();
  // phase 2: LN2 from LDS -> P (f16 A-tile)
  for (int r = wid; r < 32; r += 8) {
    float2 v = { X2[r][lane*2], X2[r][lane*2 + 1] };
    float s = v.x + v.y, sq = v.x*v.x + v.y*v.y;
    #pragma unroll
    for (int o = 1; o < 64; o <<= 1) { s += __shfl_xor(s, o); sq += __shfl_xor(sq, o); }
    float mu = s * 0.0078125f;
    float rstd = rsqrtf(sq*0.0078125f - mu*mu + 1e-5f);
    int c = lane*2;
    half2_t hv = { (_Float16)((v.x-mu)*rstd*g2[c]   + b2[c]),
                   (_Float16)((v.y-mu)*rstd*g2[c+1] + b2[c+1]) };
    *(half2_t*)&P[r][c] = hv;
  }
  __syncthreads();
  // phase 3: FC1 GEMM, wave -> 64-col stripe; GELU -> hid (f16)
  {
    const _Float16* bp = fc1_wT + (size_t)(wid*64 + lo)*128 + grp*8;
    float4_t a00={0,0,0,0}, a01={0,0,0,0}, a02={0,0,0,0}, a03={0,0,0,0};
    float4_t a10={0,0,0,0}, a11={0,0,0,0}, a12={0,0,0,0}, a13={0,0,0,0};
    #pragma unroll
    for (int kk = 0; kk < 128; kk += 32) {
      half8_t f0 = *(const half8_t*)&P[lo][kk + grp*8];
      half8_t f1 = *(const half8_t*)&P[16 + lo][kk + grp*8];
      half8_t b0 = *(const half8_t*)(bp + kk);
      half8_t b1 = *(const half8_t*)(bp + kk + (size_t)16*128);
      half8_t b2 = *(const half8_t*)(bp + kk + (size_t)32*128);
      half8_t b3 = *(const half8_t*)(bp + kk + (size_t)48*128);
      a00 = MFMA32(f0, b0, a00);  a01 = MFMA32(f0, b1, a01);
      a02 = MFMA32(f0, b2, a02);  a03 = MFMA32(f0, b3, a03);
      a10 = MFMA32(f1, b0, a10);  a11 = MFMA32(f1, b1, a11);
      a12 = MFMA32(f1, b2, a12);  a13 = MFMA32(f1, b3, a13);
    }
    int row0 = mt*32 + grp*4;
    int colb = wid*64 + lo;
    #pragma unroll
    for (int r = 0; r < 4; ++r) {
      float vv[8] = { a00[r], a01[r], a02[r], a03[r], a10[r], a11[r], a12[r], a13[r] };
      #pragma unroll
      for (int j = 0; j < 8; ++j) {
        int rr  = row0 + r + (j >= 4 ? 16 : 0);
        int col = colb + (j & 3)*16;
        float v = vv[j] + fc1_b[col];
        float g = 0.5f * v * (1.0f + erff(v * 0.70710678118654752f));
        hid[(size_t)rr*512 + col] = (_Float16)g;
      }
    }
  }
}

// ---------------- K5: FC2 + bias + residual -> out ----------------
__global__ __launch_bounds__(256) void k_fc2(
    const _Float16* __restrict__ hid, const _Float16* __restrict__ fc2_wT,
    const float* __restrict__ fc2_b, const float* __restrict__ x2,
    float* __restrict__ out)
{
  int gw = blockIdx.x*4 + (threadIdx.x >> 6);
  int nb = gw / 1372;
  int mt = gw - nb*1372;
  int lane = threadIdx.x & 63, lo = lane & 15, grp = lane >> 4;
  const _Float16* ap = hid + (size_t)(mt*16 + lo)*512 + grp*8;
  const _Float16* bp = fc2_wT + (size_t)(nb*64 + lo)*512 + grp*8;
  float4_t acc0 = {0,0,0,0}, acc1 = {0,0,0,0}, acc2 = {0,0,0,0}, acc3 = {0,0,0,0};
  for (int kk = 0; kk < 512; kk += 32) {
    half8_t a  = *(const half8_t*)(ap + kk);
    half8_t b0 = *(const half8_t*)(bp + kk);
    half8_t b1 = *(const half8_t*)(bp + kk + (size_t)16*512);
    half8_t b2 = *(const half8_t*)(bp + kk + (size_t)32*512);
    half8_t b3 = *(const half8_t*)(bp + kk + (size_t)48*512);
    acc0 = MFMA32(a, b0, acc0);
    acc1 = MFMA32(a, b1, acc1);
    acc2 = MFMA32(a, b2, acc2);
    acc3 = MFMA32(a, b3, acc3);
  }
  int rowb = mt*16 + grp*4;
  int colb = nb*64 + lo;
  #pragma unroll
  for (int r = 0; r < 4; ++r) {
    int row = rowb + r;
    out[(size_t)row*128 + colb]      = x2[(size_t)row*128 + colb]      + acc0[r] + fc2_b[colb];
    out[(size_t)row*128 + colb + 16] = x2[(size_t)row*128 + colb + 16] + acc1[r] + fc2_b[colb+16];
    out[(size_t)row*128 + colb + 32] = x2[(size_t)row*128 + colb + 32] + acc2[r] + fc2_b[colb+32];
    out[(size_t)row*128 + colb + 48] = x2[(size_t)row*128 + colb + 48] + acc3[r] + fc2_b[colb+48];
  }
}

extern "C" void kernel_launch(void* const* d_in, const int* in_sizes, int n_in,
                              void* d_out, int out_size, void* d_ws, size_t ws_size,
                              hipStream_t stream)
{
  const float* x      = (const float*)d_in[0];
  // d_in[1] mask_matrix, d_in[15] rel_index: reproduced analytically in-kernel
  const float* g1     = (const float*)d_in[2];
  const float* b1     = (const float*)d_in[3];
  const float* qkv_w  = (const float*)d_in[4];
  const float* qkv_b  = (const float*)d_in[5];
  const float* rpb    = (const float*)d_in[6];
  const float* proj_w = (const float*)d_in[7];
  const float* proj_b = (const float*)d_in[8];
  const float* g2     = (const float*)d_in[9];
  const float* b2     = (const float*)d_in[10];
  const float* fc1_w  = (const float*)d_in[11];
  const float* fc1_b  = (const float*)d_in[12];
  const float* fc2_w  = (const float*)d_in[13];
  const float* fc2_b  = (const float*)d_in[14];
  char* ws = (char*)d_ws;
  size_t o = 0;
  auto alloc = [&](size_t bytes) { size_t r = o; o += (bytes + 255) & ~size_t(255); return r; };
  size_t oOB  = alloc((size_t)NTOK*128*2);  // obuf (attn out, token order)
  size_t oX2  = alloc((size_t)NTOK*128*4);  // x2 = shortcut + proj out, fp32
  size_t oU   = alloc((size_t)NTOK*512*2);  // qkvb then hid (sequentially dead, aliased)
  size_t oWQ  = alloc(49152*2);
  size_t oWP  = alloc(16384*2);
  size_t oW1  = alloc(65536*2);
  size_t oW2  = alloc(65536*2);
  size_t oBT  = alloc((size_t)8*343*352*2); // bias table f16 (log2 domain)
  size_t oBM  = alloc((size_t)8*343*11*4);  // mask bitmasks
  (void)ws_size; (void)in_sizes; (void)n_in; (void)out_size;
  _Float16* obuf   = (_Float16*)(ws + oOB);
  float*    x2     = (float*)(ws + oX2);
  _Float16* qkvb   = (_Float16*)(ws + oU);
  _Float16* hid    = (_Float16*)(ws + oU);
  _Float16* qkv_wT = (_Float16*)(ws + oWQ);
  _Float16* proj_wT= (_Float16*)(ws + oWP);
  _Float16* fc1_wT = (_Float16*)(ws + oW1);
  _Float16* fc2_wT = (_Float16*)(ws + oW2);
  _Float16* biasT  = (_Float16*)(ws + oBT);
  unsigned* bmask  = (unsigned*)(ws + oBM);
  float*    out    = (float*)d_out;

  k_precomp<<<4662, 256, 0, stream>>>(qkv_w, proj_w, fc1_w, fc2_w, rpb,
                                      qkv_wT, proj_wT, fc1_wT, fc2_wT, biasT, bmask);
  k_qkv<<<686, 384, 0, stream>>>(x, g1, b1, qkv_wT, qkv_b, qkvb);
  k_attn<<<512, 512, 0, stream>>>(qkvb, biasT, bmask, obuf);
  k_mlp<<<686, 512, 0, stream>>>(obuf, proj_wT, proj_b, x, g2, b2,
                                 fc1_wT, fc1_b, x2, hid);
  k_fc2<<<686, 256, 0, stream>>>(hid, fc2_wT, fc2_b, x2, out);
}

// Round 8
// 106.293 us; speedup vs baseline: 1.2906x; 1.1937x over previous
//
#include <hip/hip_runtime.h>
#include <hip/hip_bf16.h>
#include <math.h>

typedef _Float16 half2_t __attribute__((ext_vector_type(2)));
typedef _Float16 half4_t __attribute__((ext_vector_type(4)));
typedef _Float16 half8_t __attribute__((ext_vector_type(8)));
typedef float float4_t __attribute__((ext_vector_type(4)));

#define MFMA16(a,b,c) __builtin_amdgcn_mfma_f32_16x16x16f16((a),(b),(c),0,0,0)
#define MFMA32(a,b,c) __builtin_amdgcn_mfma_f32_16x16x32_f16((a),(b),(c),0,0,0)

static __device__ __forceinline__ half2_t cvt_pk(float a, float b) {
  return __builtin_bit_cast(half2_t, __builtin_amdgcn_cvt_pkrtz(a, b));
}

static constexpr int NTOK = 21952;   // 64 windows * 343 tokens
static constexpr int NREG = 5488;    // 343*16 elems per (which,w,h) region
static constexpr float LOG2E = 1.44269504088896340736f;

// region id for mask: cls bits = (sz==1)<<2 | (sy==3)<<1 | (sx==3)
__device__ __forceinline__ int rid_of(int cls, int n) {
  int z = n / 49, r = n - z*49, y = r / 7, x = r - y*7;
  int rs = (cls & 4) ? (z < 4 ? 1 : 2) : 0;
  int rh = (cls & 2) ? (y < 4 ? 1 : 2) : 0;
  int rw = (cls & 1) ? (x < 4 ? 1 : 2) : 0;
  return rs*9 + rh*3 + rw;
}

// ---------------- K0: weight transposes + bias table (log2e) + mask bitmasks ----------------
__global__ __launch_bounds__(256) void k_precomp(
    const float* __restrict__ qkv_w, const float* __restrict__ proj_w,
    const float* __restrict__ fc1_w, const float* __restrict__ fc2_w,
    const float* __restrict__ rpb,
    _Float16* __restrict__ qkv_wT, _Float16* __restrict__ proj_wT,
    _Float16* __restrict__ fc1_wT, _Float16* __restrict__ fc2_wT,
    _Float16* __restrict__ biasT, unsigned* __restrict__ bmask)
{
  int i = blockIdx.x * 256 + threadIdx.x;
  if (i < 49152) { int n = i >> 7, k = i & 127; qkv_wT[i] = (_Float16)qkv_w[k*384 + n]; return; }
  i -= 49152;
  if (i < 16384) { int n = i >> 7, k = i & 127; proj_wT[i] = (_Float16)proj_w[k*128 + n]; return; }
  i -= 16384;
  if (i < 65536) { int n = i >> 7, k = i & 127; fc1_wT[i] = (_Float16)fc1_w[k*512 + n]; return; }
  i -= 65536;
  if (i < 65536) { int n = i >> 9, k = i & 511; fc2_wT[i] = (_Float16)fc2_w[k*128 + n]; return; }
  i -= 65536;
  if (i < 8*343*352) {
    int h = i / (343*352); int r = i - h*343*352; int q = r / 352; int k = r - q*352;
    _Float16 v;
    if (k >= 343) v = (_Float16)(-30000.f);          // exp2 -> 0
    else {
      int zq = q/49, rq_ = q - zq*49, yq = rq_/7, xq = rq_ - yq*7;
      int zk = k/49, rk_ = k - zk*49, yk = rk_/7, xk = rk_ - yk*7;
      int idx = 20*(yq - yk + 6) + 13*(zq - zk + 6) + (xq - xk + 6);
      v = (_Float16)(rpb[idx*8 + h] * LOG2E);        // log2-domain bias
    }
    biasT[i] = v;
    return;
  }
  i -= 8*343*352;
  if (i < 8*343*11) {
    int cls = i / (343*11); int r = i - cls*343*11; int q = r / 11; int kt = r - q*11;
    int rq = rid_of(cls, q);
    unsigned wbits = 0u;
    for (int j = 0; j < 32; ++j) {
      int k = kt*32 + j;
      if (k < 343 && rid_of(cls, k) == rq) wbits |= (1u << j);
    }
    bmask[i] = wbits;
  }
}

// ---------------- QKV epilogue (scatter to per-(w,h) q/k/v regions) ----------------
__device__ __forceinline__ void qkv_store(int row, int col, float v,
    const float* __restrict__ bias, _Float16* __restrict__ outh)
{
  v += bias[col];
  int which = col >> 7;
  if (which == 0) v *= 0.25f;                 // SCALE = (C/NH)^-0.5
  int hh = (col >> 4) & 7, d = col & 15;
  int w = row / 343, n = row - w*343;
  size_t base = (size_t)((which*64 + w)*8 + hh)*NREG;
  if (which == 2) outh[base + d*343 + n] = (_Float16)v;   // V^T layout
  else            outh[base + n*16  + d] = (_Float16)v;
}

// ---------------- K1: fused LN1(+roll+partition) + QKV GEMM ----------------
__global__ __launch_bounds__(384) void k_qkv(
    const float* __restrict__ x, const float* __restrict__ g1, const float* __restrict__ b1,
    const _Float16* __restrict__ qkv_wT, const float* __restrict__ qkv_b,
    _Float16* __restrict__ qkvb)
{
  __shared__ _Float16 A[32][136];   // +8 pad: 272B row stride -> 2-way bank alias (free)
  int mt = blockIdx.x;
  int tid = threadIdx.x, wid = tid >> 6, lane = tid & 63;
  for (int r = wid; r < 32; r += 6) {
    int row = mt*32 + r;
    int w = row / 343, n = row - w*343;
    int b = w >> 5, widx = w & 31;
    int sz = widx >> 4, sy = (widx >> 2) & 3, sx = widx & 3;
    int z = n / 49, rem = n - z*49, y = rem / 7, xx = rem - y*7;
    int gs = sz*7 + z + 3;  if (gs >= 14) gs -= 14;
    int gh = sy*7 + y + 3;  if (gh >= 28) gh -= 28;
    int gw = sx*7 + xx + 3; if (gw >= 28) gw -= 28;
    int gt = b*10976 + (gs*28 + gh)*28 + gw;
    const float* xr = x + (size_t)gt*128;
    float2 v = *(const float2*)(xr + lane*2);
    float s = v.x + v.y, sq = v.x*v.x + v.y*v.y;
    #pragma unroll
    for (int o = 1; o < 64; o <<= 1) { s += __shfl_xor(s, o); sq += __shfl_xor(sq, o); }
    float mu = s * 0.0078125f;
    float rstd = rsqrtf(sq*0.0078125f - mu*mu + 1e-5f);
    int c = lane*2;
    half2_t hv = { (_Float16)((v.x-mu)*rstd*g1[c]   + b1[c]),
                   (_Float16)((v.y-mu)*rstd*g1[c+1] + b1[c+1]) };
    *(half2_t*)&A[r][c] = hv;
  }
  __syncthreads();
  int lo = lane & 15, grp = lane >> 4;
  const _Float16* bp = qkv_wT + (size_t)(wid*64 + lo)*128 + grp*8;
  float4_t a00={0,0,0,0}, a01={0,0,0,0}, a02={0,0,0,0}, a03={0,0,0,0};
  float4_t a10={0,0,0,0}, a11={0,0,0,0}, a12={0,0,0,0}, a13={0,0,0,0};
  #pragma unroll
  for (int kk = 0; kk < 128; kk += 32) {
    half8_t f0 = *(const half8_t*)&A[lo][kk + grp*8];
    half8_t f1 = *(const half8_t*)&A[16 + lo][kk + grp*8];
    half8_t b0 = *(const half8_t*)(bp + kk);
    half8_t b1 = *(const half8_t*)(bp + kk + (size_t)16*128);
    half8_t b2 = *(const half8_t*)(bp + kk + (size_t)32*128);
    half8_t b3 = *(const half8_t*)(bp + kk + (size_t)48*128);
    a00 = MFMA32(f0, b0, a00);  a01 = MFMA32(f0, b1, a01);
    a02 = MFMA32(f0, b2, a02);  a03 = MFMA32(f0, b3, a03);
    a10 = MFMA32(f1, b0, a10);  a11 = MFMA32(f1, b1, a11);
    a12 = MFMA32(f1, b2, a12);  a13 = MFMA32(f1, b3, a13);
  }
  int row0 = mt*32 + grp*4;
  int colb = wid*64 + lo;
  #pragma unroll
  for (int r = 0; r < 4; ++r) {
    qkv_store(row0+r,    colb,    a00[r], qkv_b, qkvb);
    qkv_store(row0+r,    colb+16, a01[r], qkv_b, qkvb);
    qkv_store(row0+r,    colb+32, a02[r], qkv_b, qkvb);
    qkv_store(row0+r,    colb+48, a03[r], qkv_b, qkvb);
    qkv_store(row0+16+r, colb,    a10[r], qkv_b, qkvb);
    qkv_store(row0+16+r, colb+16, a11[r], qkv_b, qkvb);
    qkv_store(row0+16+r, colb+32, a12[r], qkv_b, qkvb);
    qkv_store(row0+16+r, colb+48, a13[r], qkv_b, qkvb);
  }
}

// ---------------- K3: windowed attention (R7 core, token-order output) ----------------
__global__ __launch_bounds__(512) void k_attn(
    const _Float16* __restrict__ qkv, const _Float16* __restrict__ biasT,
    const unsigned* __restrict__ bmask, _Float16* __restrict__ obuf)
{
  __shared__ _Float16 Klds[352][24];
  __shared__ _Float16 VTlds[16][360];
  int bx = blockIdx.x;
  int w = bx >> 3, h = bx & 7;
  int b = w >> 5, widx = w & 31;
  int sz = widx >> 4, sy = (widx >> 2) & 3, sx = widx & 3;
  int cls = (sz << 2) | (sy == 3 ? 2 : 0) | (sx == 3 ? 1 : 0);
  int tid = threadIdx.x;
  const _Float16* qp  = qkv + (size_t)(w*8 + h) * NREG;
  const _Float16* kp  = qp + (size_t)512  * NREG;
  const _Float16* vtp = qp + (size_t)1024 * NREG;   // [d][n]
  for (int c = tid; c < 704; c += 512) {
    int n = c >> 1, d0 = (c & 1) * 8;
    half8_t kv = {};
    if (n < 343) kv = *(const half8_t*)(kp + n*16 + d0);
    *(half8_t*)&Klds[n][d0] = kv;
  }
  for (int c = tid; c < 704; c += 512) {
    int d = c / 44, n0 = (c - d*44) * 8;
    half8_t vv = {};
    if (n0 + 8 <= 343) vv = *(const half8_t*)(vtp + d*343 + n0);
    else { for (int j = 0; j < 8; ++j) vv[j] = (n0 + j < 343) ? vtp[d*343 + n0 + j] : (_Float16)0.f; }
    *(half8_t*)&VTlds[d][n0] = vv;
  }
  __syncthreads();
  int lane = tid & 63, lo = lane & 15, grp = lane >> 4;
  int wid = tid >> 6;
  for (int qt = wid; qt < 22; qt += 8) {
    int q  = qt*16 + lo;
    int qv = q < 343 ? q : 342;
    half4_t qf = *(const half4_t*)(qp + (size_t)qv*16 + grp*4);
    const _Float16* bp  = biasT + (size_t)(h*343 + qv)*352;
    const unsigned* bmp = bmask + (size_t)(cls*343 + qv)*11;
    half4_t barr0[11], barr1[11];
    unsigned bmarr[11];
    #pragma unroll
    for (int kt = 0; kt < 11; ++kt) {
      barr0[kt] = *(const half4_t*)(bp + kt*32 + grp*4);
      barr1[kt] = *(const half4_t*)(bp + kt*32 + 16 + grp*4);
      bmarr[kt] = bmp[kt];
    }
    float lsum = 0.f;
    float4_t acc = {0.f, 0.f, 0.f, 0.f};
    #pragma unroll
    for (int kt = 0; kt < 11; ++kt) {
      int kb = kt*32;
      half4_t ka0 = *(const half4_t*)&Klds[kb + lo][grp*4];
      half4_t ka1 = *(const half4_t*)&Klds[kb + 16 + lo][grp*4];
      float4_t zero = {0.f, 0.f, 0.f, 0.f};
      float4_t s0 = MFMA16(ka0, qf, zero);
      float4_t s1 = MFMA16(ka1, qf, zero);
      unsigned bmw = bmarr[kt];
      float p[8];
      #pragma unroll
      for (int i = 0; i < 8; ++i) {
        float sv = (i < 4) ? s0[i] : s1[i-4];
        float bb = (float)((i < 4) ? barr0[kt][i] : barr1[kt][i-4]);
        float e = exp2f(fmaf(sv, LOG2E, bb));
        unsigned bit = (bmw >> ((i >> 2)*16 + grp*4 + (i & 3))) & 1u;
        p[i] = bit ? e : 0.f;
        lsum += p[i];
      }
      half2_t pk01 = cvt_pk(p[0], p[1]);
      half2_t pk23 = cvt_pk(p[2], p[3]);
      half2_t pk45 = cvt_pk(p[4], p[5]);
      half2_t pk67 = cvt_pk(p[6], p[7]);
      half4_t pb0 = __builtin_shufflevector(pk01, pk23, 0, 1, 2, 3);
      half4_t pb1 = __builtin_shufflevector(pk45, pk67, 0, 1, 2, 3);
      half4_t va0 = *(const half4_t*)&VTlds[lo][kb + grp*4];
      half4_t va1 = *(const half4_t*)&VTlds[lo][kb + 16 + grp*4];
      acc = MFMA16(va0, pb0, acc);
      acc = MFMA16(va1, pb1, acc);
    }
    lsum += __shfl_xor(lsum, 16);
    lsum += __shfl_xor(lsum, 32);
    if (q < 343) {
      // token-order output row (roll + window-reverse analytic)
      int z = q/49, rem = q - z*49, y = rem/7, xx = rem - y*7;
      int gs = sz*7 + z + 3;  if (gs >= 14) gs -= 14;
      int gh = sy*7 + y + 3;  if (gh >= 28) gh -= 28;
      int gw = sx*7 + xx + 3; if (gw >= 28) gw -= 28;
      int gt = b*10976 + (gs*28 + gh)*28 + gw;
      float rl = 1.f / lsum;
      half4_t o4 = { (_Float16)(acc[0]*rl), (_Float16)(acc[1]*rl),
                     (_Float16)(acc[2]*rl), (_Float16)(acc[3]*rl) };
      *(half4_t*)(obuf + (size_t)gt*128 + h*16 + grp*4) = o4;
    }
  }
}

// ---------------- K4: fused proj + residual + LN2 + FC1 + GELU + FC2 + residual ----------------
// Block owns 32 token rows end-to-end; hid tile lives entirely in LDS (H), so the
// 22.5MB hid and 11.2MB x2 global roundtrips are eliminated.
__global__ __launch_bounds__(512) void k_mlp(
    const _Float16* __restrict__ obuf, const _Float16* __restrict__ proj_wT,
    const float* __restrict__ proj_b, const float* __restrict__ x,
    const float* __restrict__ g2, const float* __restrict__ b2,
    const _Float16* __restrict__ fc1_wT, const float* __restrict__ fc1_b,
    const _Float16* __restrict__ fc2_wT, const float* __restrict__ fc2_b,
    float* __restrict__ out)
{
  __shared__ _Float16 P[32][136];   // attn-out rows; later reused as LN'd FC1 A-tile (8.7KB)
  __shared__ float    X2[32][132];  // shortcut + proj (16.9KB)
  __shared__ _Float16 H[32][520];   // GELU(fc1) tile (33.3KB) -> total 58.9KB, 2 blocks/CU
  int mt = blockIdx.x;
  int tid = threadIdx.x, wid = tid >> 6, lane = tid & 63, lo = lane & 15, grp = lane >> 4;
  // phase 0: copy attention-output rows (token order, contiguous) into LDS
  for (int r = wid; r < 32; r += 8) {
    int row = mt*32 + r;
    half2_t v = *(const half2_t*)(obuf + (size_t)row*128 + lane*2);
    *(half2_t*)&P[r][lane*2] = v;
  }
  __syncthreads();
  // phase 1: proj GEMM, wave -> 16-col stripe; +bias +shortcut -> X2 (LDS only)
  {
    const _Float16* bp = proj_wT + (size_t)(wid*16 + lo)*128 + grp*8;
    float4_t a0={0,0,0,0}, a1={0,0,0,0};
    #pragma unroll
    for (int kk = 0; kk < 128; kk += 32) {
      half8_t f0 = *(const half8_t*)&P[lo][kk + grp*8];
      half8_t f1 = *(const half8_t*)&P[16 + lo][kk + grp*8];
      half8_t b0 = *(const half8_t*)(bp + kk);
      a0 = MFMA32(f0, b0, a0);
      a1 = MFMA32(f1, b0, a1);
    }
    int colb = wid*16 + lo;
    float bb = proj_b[colb];
    #pragma unroll
    for (int r = 0; r < 4; ++r) {
      int r0 = grp*4 + r;
      int row0 = mt*32 + r0, row1 = row0 + 16;
      X2[r0][colb]    = x[(size_t)row0*128 + colb] + a0[r] + bb;
      X2[r0+16][colb] = x[(size_t)row1*128 + colb] + a1[r] + bb;
    }
  }
  __syncthreads();
  // phase 2: LN2 from LDS -> P (f16 A-tile)
  for (int r = wid; r < 32; r += 8) {
    float2 v = { X2[r][lane*2], X2[r][lane*2 + 1] };
    float s = v.x + v.y, sq = v.x*v.x + v.y*v.y;
    #pragma unroll
    for (int o = 1; o < 64; o <<= 1) { s += __shfl_xor(s, o); sq += __shfl_xor(sq, o); }
    float mu = s * 0.0078125f;
    float rstd = rsqrtf(sq*0.0078125f - mu*mu + 1e-5f);
    int c = lane*2;
    half2_t hv = { (_Float16)((v.x-mu)*rstd*g2[c]   + b2[c]),
                   (_Float16)((v.y-mu)*rstd*g2[c+1] + b2[c+1]) };
    *(half2_t*)&P[r][c] = hv;
  }
  __syncthreads();
  // phase 3: FC1 GEMM, wave -> 64-col stripe; GELU -> H (LDS)
  {
    const _Float16* bp = fc1_wT + (size_t)(wid*64 + lo)*128 + grp*8;
    float4_t a00={0,0,0,0}, a01={0,0,0,0}, a02={0,0,0,0}, a03={0,0,0,0};
    float4_t a10={0,0,0,0}, a11={0,0,0,0}, a12={0,0,0,0}, a13={0,0,0,0};
    #pragma unroll
    for (int kk = 0; kk < 128; kk += 32) {
      half8_t f0 = *(const half8_t*)&P[lo][kk + grp*8];
      half8_t f1 = *(const half8_t*)&P[16 + lo][kk + grp*8];
      half8_t b0 = *(const half8_t*)(bp + kk);
      half8_t b1 = *(const half8_t*)(bp + kk + (size_t)16*128);
      half8_t b2 = *(const half8_t*)(bp + kk + (size_t)32*128);
      half8_t b3 = *(const half8_t*)(bp + kk + (size_t)48*128);
      a00 = MFMA32(f0, b0, a00);  a01 = MFMA32(f0, b1, a01);
      a02 = MFMA32(f0, b2, a02);  a03 = MFMA32(f0, b3, a03);
      a10 = MFMA32(f1, b0, a10);  a11 = MFMA32(f1, b1, a11);
      a12 = MFMA32(f1, b2, a12);  a13 = MFMA32(f1, b3, a13);
    }
    int colb = wid*64 + lo;
    #pragma unroll
    for (int r = 0; r < 4; ++r) {
      float vv[8] = { a00[r], a01[r], a02[r], a03[r], a10[r], a11[r], a12[r], a13[r] };
      #pragma unroll
      for (int j = 0; j < 8; ++j) {
        int rr  = grp*4 + r + (j >= 4 ? 16 : 0);
        int col = colb + (j & 3)*16;
        float v = vv[j] + fc1_b[col];
        float g = 0.5f * v * (1.0f + erff(v * 0.70710678118654752f));
        H[rr][col] = (_Float16)g;
      }
    }
  }
  __syncthreads();
  // phase 4: FC2 GEMM from H, wave -> 16-col stripe; +bias +X2 residual -> out
  {
    const _Float16* bp = fc2_wT + (size_t)(wid*16 + lo)*512 + grp*8;
    float4_t c0={0,0,0,0}, c1={0,0,0,0};
    #pragma unroll
    for (int kk = 0; kk < 512; kk += 32) {
      half8_t f0 = *(const half8_t*)&H[lo][kk + grp*8];
      half8_t f1 = *(const half8_t*)&H[16 + lo][kk + grp*8];
      half8_t b0 = *(const half8_t*)(bp + kk);
      c0 = MFMA32(f0, b0, c0);
      c1 = MFMA32(f1, b0, c1);
    }
    int colb = wid*16 + lo;
    float bb = fc2_b[colb];
    #pragma unroll
    for (int r = 0; r < 4; ++r) {
      int r0 = grp*4 + r;
      int row0 = mt*32 + r0;
      out[(size_t)row0*128 + colb]      = X2[r0][colb]    + c0[r] + bb;
      out[(size_t)(row0+16)*128 + colb] = X2[r0+16][colb] + c1[r] + bb;
    }
  }
}

extern "C" void kernel_launch(void* const* d_in, const int* in_sizes, int n_in,
                              void* d_out, int out_size, void* d_ws, size_t ws_size,
                              hipStream_t stream)
{
  const float* x      = (const float*)d_in[0];
  // d_in[1] mask_matrix, d_in[15] rel_index: reproduced analytically in-kernel
  const float* g1     = (const float*)d_in[2];
  const float* b1     = (const float*)d_in[3];
  const float* qkv_w  = (const float*)d_in[4];
  const float* qkv_b  = (const float*)d_in[5];
  const float* rpb    = (const float*)d_in[6];
  const float* proj_w = (const float*)d_in[7];
  const float* proj_b = (const float*)d_in[8];
  const float* g2     = (const float*)d_in[9];
  const float* b2     = (const float*)d_in[10];
  const float* fc1_w  = (const float*)d_in[11];
  const float* fc1_b  = (const float*)d_in[12];
  const float* fc2_w  = (const float*)d_in[13];
  const float* fc2_b  = (const float*)d_in[14];
  char* ws = (char*)d_ws;
  size_t o = 0;
  auto alloc = [&](size_t bytes) { size_t r = o; o += (bytes + 255) & ~size_t(255); return r; };
  size_t oOB  = alloc((size_t)NTOK*128*2);  // obuf (attn out, token order)
  size_t oU   = alloc((size_t)NTOK*512*2);  // qkvb
  size_t oWQ  = alloc(49152*2);
  size_t oWP  = alloc(16384*2);
  size_t oW1  = alloc(65536*2);
  size_t oW2  = alloc(65536*2);
  size_t oBT  = alloc((size_t)8*343*352*2); // bias table f16 (log2 domain)
  size_t oBM  = alloc((size_t)8*343*11*4);  // mask bitmasks
  (void)ws_size; (void)in_sizes; (void)n_in; (void)out_size;
  _Float16* obuf   = (_Float16*)(ws + oOB);
  _Float16* qkvb   = (_Float16*)(ws + oU);
  _Float16* qkv_wT = (_Float16*)(ws + oWQ);
  _Float16* proj_wT= (_Float16*)(ws + oWP);
  _Float16* fc1_wT = (_Float16*)(ws + oW1);
  _Float16* fc2_wT = (_Float16*)(ws + oW2);
  _Float16* biasT  = (_Float16*)(ws + oBT);
  unsigned* bmask  = (unsigned*)(ws + oBM);
  float*    out    = (float*)d_out;

  k_precomp<<<4662, 256, 0, stream>>>(qkv_w, proj_w, fc1_w, fc2_w, rpb,
                                      qkv_wT, proj_wT, fc1_wT, fc2_wT, biasT, bmask);
  k_qkv<<<686, 384, 0, stream>>>(x, g1, b1, qkv_wT, qkv_b, qkvb);
  k_attn<<<512, 512, 0, stream>>>(qkvb, biasT, bmask, obuf);
  k_mlp<<<686, 512, 0, stream>>>(obuf, proj_wT, proj_b, x, g2, b2,
                                 fc1_wT, fc1_b, fc2_wT, fc2_b, out);
}

// Round 9
// 106.202 us; speedup vs baseline: 1.2917x; 1.0009x over previous
//
#include <hip/hip_runtime.h>
#include <hip/hip_bf16.h>
#include <math.h>

typedef _Float16 half2_t __attribute__((ext_vector_type(2)));
typedef _Float16 half4_t __attribute__((ext_vector_type(4)));
typedef _Float16 half8_t __attribute__((ext_vector_type(8)));
typedef float float4_t __attribute__((ext_vector_type(4)));

#define MFMA16(a,b,c) __builtin_amdgcn_mfma_f32_16x16x16f16((a),(b),(c),0,0,0)
#define MFMA32(a,b,c) __builtin_amdgcn_mfma_f32_16x16x32_f16((a),(b),(c),0,0,0)

static __device__ __forceinline__ half2_t cvt_pk(float a, float b) {
  return __builtin_bit_cast(half2_t, __builtin_amdgcn_cvt_pkrtz(a, b));
}

static constexpr int NTOK = 21952;   // 64 windows * 343 tokens
static constexpr int NREG = 5488;    // 343*16 elems per (which,w,h) region
static constexpr float LOG2E = 1.44269504088896340736f;

// region id for mask: cls bits = (sz==1)<<2 | (sy==3)<<1 | (sx==3)
__device__ __forceinline__ int rid_of(int cls, int n) {
  int z = n / 49, r = n - z*49, y = r / 7, x = r - y*7;
  int rs = (cls & 4) ? (z < 4 ? 1 : 2) : 0;
  int rh = (cls & 2) ? (y < 4 ? 1 : 2) : 0;
  int rw = (cls & 1) ? (x < 4 ? 1 : 2) : 0;
  return rs*9 + rh*3 + rw;
}

// ---------------- K0: weight transposes + bias table (log2e) + mask bitmasks ----------------
__global__ __launch_bounds__(256) void k_precomp(
    const float* __restrict__ qkv_w, const float* __restrict__ proj_w,
    const float* __restrict__ fc1_w, const float* __restrict__ fc2_w,
    const float* __restrict__ rpb,
    _Float16* __restrict__ qkv_wT, _Float16* __restrict__ proj_wT,
    _Float16* __restrict__ fc1_wT, _Float16* __restrict__ fc2_wT,
    _Float16* __restrict__ biasT, unsigned* __restrict__ bmask)
{
  int i = blockIdx.x * 256 + threadIdx.x;
  if (i < 49152) { int n = i >> 7, k = i & 127; qkv_wT[i] = (_Float16)qkv_w[k*384 + n]; return; }
  i -= 49152;
  if (i < 16384) { int n = i >> 7, k = i & 127; proj_wT[i] = (_Float16)proj_w[k*128 + n]; return; }
  i -= 16384;
  if (i < 65536) { int n = i >> 7, k = i & 127; fc1_wT[i] = (_Float16)fc1_w[k*512 + n]; return; }
  i -= 65536;
  if (i < 65536) { int n = i >> 9, k = i & 511; fc2_wT[i] = (_Float16)fc2_w[k*128 + n]; return; }
  i -= 65536;
  if (i < 8*343*352) {
    int h = i / (343*352); int r = i - h*343*352; int q = r / 352; int k = r - q*352;
    _Float16 v;
    if (k >= 343) v = (_Float16)(-30000.f);          // exp2 -> 0
    else {
      int zq = q/49, rq_ = q - zq*49, yq = rq_/7, xq = rq_ - yq*7;
      int zk = k/49, rk_ = k - zk*49, yk = rk_/7, xk = rk_ - yk*7;
      int idx = 20*(yq - yk + 6) + 13*(zq - zk + 6) + (xq - xk + 6);
      v = (_Float16)(rpb[idx*8 + h] * LOG2E);        // log2-domain bias
    }
    biasT[i] = v;
    return;
  }
  i -= 8*343*352;
  if (i < 8*343*11) {
    int cls = i / (343*11); int r = i - cls*343*11; int q = r / 11; int kt = r - q*11;
    int rq = rid_of(cls, q);
    unsigned wbits = 0u;
    for (int j = 0; j < 32; ++j) {
      int k = kt*32 + j;
      if (k < 343 && rid_of(cls, k) == rq) wbits |= (1u << j);
    }
    bmask[i] = wbits;
  }
}

// ---------------- QKV epilogue (scatter to per-(w,h) q/k/v regions) ----------------
__device__ __forceinline__ void qkv_store(int row, int col, float v,
    const float* __restrict__ bias, _Float16* __restrict__ outh)
{
  v += bias[col];
  int which = col >> 7;
  if (which == 0) v *= 0.25f;                 // SCALE = (C/NH)^-0.5
  int hh = (col >> 4) & 7, d = col & 15;
  int w = row / 343, n = row - w*343;
  size_t base = (size_t)((which*64 + w)*8 + hh)*NREG;
  if (which == 2) outh[base + d*343 + n] = (_Float16)v;   // V^T layout
  else            outh[base + n*16  + d] = (_Float16)v;
}

// ---------------- K1: fused LN1(+roll+partition) + QKV GEMM ----------------
__global__ __launch_bounds__(384) void k_qkv(
    const float* __restrict__ x, const float* __restrict__ g1, const float* __restrict__ b1,
    const _Float16* __restrict__ qkv_wT, const float* __restrict__ qkv_b,
    _Float16* __restrict__ qkvb)
{
  __shared__ _Float16 A[32][136];   // +8 pad: 272B row stride -> 2-way bank alias (free)
  int mt = blockIdx.x;
  int tid = threadIdx.x, wid = tid >> 6, lane = tid & 63;
  for (int r = wid; r < 32; r += 6) {
    int row = mt*32 + r;
    int w = row / 343, n = row - w*343;
    int b = w >> 5, widx = w & 31;
    int sz = widx >> 4, sy = (widx >> 2) & 3, sx = widx & 3;
    int z = n / 49, rem = n - z*49, y = rem / 7, xx = rem - y*7;
    int gs = sz*7 + z + 3;  if (gs >= 14) gs -= 14;
    int gh = sy*7 + y + 3;  if (gh >= 28) gh -= 28;
    int gw = sx*7 + xx + 3; if (gw >= 28) gw -= 28;
    int gt = b*10976 + (gs*28 + gh)*28 + gw;
    const float* xr = x + (size_t)gt*128;
    float2 v = *(const float2*)(xr + lane*2);
    float s = v.x + v.y, sq = v.x*v.x + v.y*v.y;
    #pragma unroll
    for (int o = 1; o < 64; o <<= 1) { s += __shfl_xor(s, o); sq += __shfl_xor(sq, o); }
    float mu = s * 0.0078125f;
    float rstd = rsqrtf(sq*0.0078125f - mu*mu + 1e-5f);
    int c = lane*2;
    half2_t hv = { (_Float16)((v.x-mu)*rstd*g1[c]   + b1[c]),
                   (_Float16)((v.y-mu)*rstd*g1[c+1] + b1[c+1]) };
    *(half2_t*)&A[r][c] = hv;
  }
  __syncthreads();
  int lo = lane & 15, grp = lane >> 4;
  const _Float16* bp = qkv_wT + (size_t)(wid*64 + lo)*128 + grp*8;
  float4_t a00={0,0,0,0}, a01={0,0,0,0}, a02={0,0,0,0}, a03={0,0,0,0};
  float4_t a10={0,0,0,0}, a11={0,0,0,0}, a12={0,0,0,0}, a13={0,0,0,0};
  #pragma unroll
  for (int kk = 0; kk < 128; kk += 32) {
    half8_t f0 = *(const half8_t*)&A[lo][kk + grp*8];
    half8_t f1 = *(const half8_t*)&A[16 + lo][kk + grp*8];
    half8_t b0 = *(const half8_t*)(bp + kk);
    half8_t b1 = *(const half8_t*)(bp + kk + (size_t)16*128);
    half8_t b2 = *(const half8_t*)(bp + kk + (size_t)32*128);
    half8_t b3 = *(const half8_t*)(bp + kk + (size_t)48*128);
    a00 = MFMA32(f0, b0, a00);  a01 = MFMA32(f0, b1, a01);
    a02 = MFMA32(f0, b2, a02);  a03 = MFMA32(f0, b3, a03);
    a10 = MFMA32(f1, b0, a10);  a11 = MFMA32(f1, b1, a11);
    a12 = MFMA32(f1, b2, a12);  a13 = MFMA32(f1, b3, a13);
  }
  int row0 = mt*32 + grp*4;
  int colb = wid*64 + lo;
  #pragma unroll
  for (int r = 0; r < 4; ++r) {
    qkv_store(row0+r,    colb,    a00[r], qkv_b, qkvb);
    qkv_store(row0+r,    colb+16, a01[r], qkv_b, qkvb);
    qkv_store(row0+r,    colb+32, a02[r], qkv_b, qkvb);
    qkv_store(row0+r,    colb+48, a03[r], qkv_b, qkvb);
    qkv_store(row0+16+r, colb,    a10[r], qkv_b, qkvb);
    qkv_store(row0+16+r, colb+16, a11[r], qkv_b, qkvb);
    qkv_store(row0+16+r, colb+32, a12[r], qkv_b, qkvb);
    qkv_store(row0+16+r, colb+48, a13[r], qkv_b, qkvb);
  }
}

// ---------------- K3: windowed attention (R7 core, token-order output) ----------------
__global__ __launch_bounds__(512) void k_attn(
    const _Float16* __restrict__ qkv, const _Float16* __restrict__ biasT,
    const unsigned* __restrict__ bmask, _Float16* __restrict__ obuf)
{
  __shared__ _Float16 Klds[352][24];
  __shared__ _Float16 VTlds[16][360];
  int bx = blockIdx.x;
  int w = bx >> 3, h = bx & 7;
  int b = w >> 5, widx = w & 31;
  int sz = widx >> 4, sy = (widx >> 2) & 3, sx = widx & 3;
  int cls = (sz << 2) | (sy == 3 ? 2 : 0) | (sx == 3 ? 1 : 0);
  int tid = threadIdx.x;
  const _Float16* qp  = qkv + (size_t)(w*8 + h) * NREG;
  const _Float16* kp  = qp + (size_t)512  * NREG;
  const _Float16* vtp = qp + (size_t)1024 * NREG;   // [d][n]
  for (int c = tid; c < 704; c += 512) {
    int n = c >> 1, d0 = (c & 1) * 8;
    half8_t kv = {};
    if (n < 343) kv = *(const half8_t*)(kp + n*16 + d0);
    *(half8_t*)&Klds[n][d0] = kv;
  }
  for (int c = tid; c < 704; c += 512) {
    int d = c / 44, n0 = (c - d*44) * 8;
    half8_t vv = {};
    if (n0 + 8 <= 343) vv = *(const half8_t*)(vtp + d*343 + n0);
    else { for (int j = 0; j < 8; ++j) vv[j] = (n0 + j < 343) ? vtp[d*343 + n0 + j] : (_Float16)0.f; }
    *(half8_t*)&VTlds[d][n0] = vv;
  }
  __syncthreads();
  int lane = tid & 63, lo = lane & 15, grp = lane >> 4;
  int wid = tid >> 6;
  for (int qt = wid; qt < 22; qt += 8) {
    int q  = qt*16 + lo;
    int qv = q < 343 ? q : 342;
    half4_t qf = *(const half4_t*)(qp + (size_t)qv*16 + grp*4);
    const _Float16* bp  = biasT + (size_t)(h*343 + qv)*352;
    const unsigned* bmp = bmask + (size_t)(cls*343 + qv)*11;
    half4_t barr0[11], barr1[11];
    unsigned bmarr[11];
    #pragma unroll
    for (int kt = 0; kt < 11; ++kt) {
      barr0[kt] = *(const half4_t*)(bp + kt*32 + grp*4);
      barr1[kt] = *(const half4_t*)(bp + kt*32 + 16 + grp*4);
      bmarr[kt] = bmp[kt];
    }
    float lsum = 0.f;
    float4_t acc = {0.f, 0.f, 0.f, 0.f};
    #pragma unroll
    for (int kt = 0; kt < 11; ++kt) {
      int kb = kt*32;
      half4_t ka0 = *(const half4_t*)&Klds[kb + lo][grp*4];
      half4_t ka1 = *(const half4_t*)&Klds[kb + 16 + lo][grp*4];
      float4_t zero = {0.f, 0.f, 0.f, 0.f};
      float4_t s0 = MFMA16(ka0, qf, zero);
      float4_t s1 = MFMA16(ka1, qf, zero);
      unsigned bmw = bmarr[kt];
      float p[8];
      #pragma unroll
      for (int i = 0; i < 8; ++i) {
        float sv = (i < 4) ? s0[i] : s1[i-4];
        float bb = (float)((i < 4) ? barr0[kt][i] : barr1[kt][i-4]);
        float e = exp2f(fmaf(sv, LOG2E, bb));
        unsigned bit = (bmw >> ((i >> 2)*16 + grp*4 + (i & 3))) & 1u;
        p[i] = bit ? e : 0.f;
        lsum += p[i];
      }
      half2_t pk01 = cvt_pk(p[0], p[1]);
      half2_t pk23 = cvt_pk(p[2], p[3]);
      half2_t pk45 = cvt_pk(p[4], p[5]);
      half2_t pk67 = cvt_pk(p[6], p[7]);
      half4_t pb0 = __builtin_shufflevector(pk01, pk23, 0, 1, 2, 3);
      half4_t pb1 = __builtin_shufflevector(pk45, pk67, 0, 1, 2, 3);
      half4_t va0 = *(const half4_t*)&VTlds[lo][kb + grp*4];
      half4_t va1 = *(const half4_t*)&VTlds[lo][kb + 16 + grp*4];
      acc = MFMA16(va0, pb0, acc);
      acc = MFMA16(va1, pb1, acc);
    }
    lsum += __shfl_xor(lsum, 16);
    lsum += __shfl_xor(lsum, 32);
    if (q < 343) {
      // token-order output row (roll + window-reverse analytic)
      int z = q/49, rem = q - z*49, y = rem/7, xx = rem - y*7;
      int gs = sz*7 + z + 3;  if (gs >= 14) gs -= 14;
      int gh = sy*7 + y + 3;  if (gh >= 28) gh -= 28;
      int gw = sx*7 + xx + 3; if (gw >= 28) gw -= 28;
      int gt = b*10976 + (gs*28 + gh)*28 + gw;
      float rl = 1.f / lsum;
      half4_t o4 = { (_Float16)(acc[0]*rl), (_Float16)(acc[1]*rl),
                     (_Float16)(acc[2]*rl), (_Float16)(acc[3]*rl) };
      *(half4_t*)(obuf + (size_t)gt*128 + h*16 + grp*4) = o4;
    }
  }
}

// ---------------- K4: fused proj + residual + LN2 + FC1 + GELU + FC2 + residual ----------------
// X2 stored f16: LDS 58.9 -> 49.5KB => 3 blocks/CU (was 2); whole 686-block grid co-resident.
__global__ __launch_bounds__(512) void k_mlp(
    const _Float16* __restrict__ obuf, const _Float16* __restrict__ proj_wT,
    const float* __restrict__ proj_b, const float* __restrict__ x,
    const float* __restrict__ g2, const float* __restrict__ b2,
    const _Float16* __restrict__ fc1_wT, const float* __restrict__ fc1_b,
    const _Float16* __restrict__ fc2_wT, const float* __restrict__ fc2_b,
    float* __restrict__ out)
{
  __shared__ _Float16 P[32][136];   // attn-out rows; later reused as LN'd FC1 A-tile (8.7KB)
  __shared__ _Float16 X2[32][136];  // shortcut + proj, f16 (8.7KB)
  __shared__ _Float16 H[32][520];   // GELU(fc1) tile (33.3KB) -> total 49.5KB, 3 blocks/CU
  int mt = blockIdx.x;
  int tid = threadIdx.x, wid = tid >> 6, lane = tid & 63, lo = lane & 15, grp = lane >> 4;
  // phase 0: copy attention-output rows (token order, contiguous) into LDS
  for (int r = wid; r < 32; r += 8) {
    int row = mt*32 + r;
    half2_t v = *(const half2_t*)(obuf + (size_t)row*128 + lane*2);
    *(half2_t*)&P[r][lane*2] = v;
  }
  __syncthreads();
  // phase 1: proj GEMM, wave -> 16-col stripe; +bias +shortcut -> X2 (LDS, f16)
  {
    const _Float16* bp = proj_wT + (size_t)(wid*16 + lo)*128 + grp*8;
    float4_t a0={0,0,0,0}, a1={0,0,0,0};
    #pragma unroll
    for (int kk = 0; kk < 128; kk += 32) {
      half8_t f0 = *(const half8_t*)&P[lo][kk + grp*8];
      half8_t f1 = *(const half8_t*)&P[16 + lo][kk + grp*8];
      half8_t b0 = *(const half8_t*)(bp + kk);
      a0 = MFMA32(f0, b0, a0);
      a1 = MFMA32(f1, b0, a1);
    }
    int colb = wid*16 + lo;
    float bb = proj_b[colb];
    #pragma unroll
    for (int r = 0; r < 4; ++r) {
      int r0 = grp*4 + r;
      int row0 = mt*32 + r0, row1 = row0 + 16;
      X2[r0][colb]    = (_Float16)(x[(size_t)row0*128 + colb] + a0[r] + bb);
      X2[r0+16][colb] = (_Float16)(x[(size_t)row1*128 + colb] + a1[r] + bb);
    }
  }
  __syncthreads();
  // phase 2: LN2 from LDS -> P (f16 A-tile)
  for (int r = wid; r < 32; r += 8) {
    half2_t hx = *(const half2_t*)&X2[r][lane*2];
    float2 v = { (float)hx[0], (float)hx[1] };
    float s = v.x + v.y, sq = v.x*v.x + v.y*v.y;
    #pragma unroll
    for (int o = 1; o < 64; o <<= 1) { s += __shfl_xor(s, o); sq += __shfl_xor(sq, o); }
    float mu = s * 0.0078125f;
    float rstd = rsqrtf(sq*0.0078125f - mu*mu + 1e-5f);
    int c = lane*2;
    half2_t hv = { (_Float16)((v.x-mu)*rstd*g2[c]   + b2[c]),
                   (_Float16)((v.y-mu)*rstd*g2[c+1] + b2[c+1]) };
    *(half2_t*)&P[r][c] = hv;
  }
  __syncthreads();
  // phase 3: FC1 GEMM, wave -> 64-col stripe; GELU -> H (LDS)
  {
    const _Float16* bp = fc1_wT + (size_t)(wid*64 + lo)*128 + grp*8;
    float4_t a00={0,0,0,0}, a01={0,0,0,0}, a02={0,0,0,0}, a03={0,0,0,0};
    float4_t a10={0,0,0,0}, a11={0,0,0,0}, a12={0,0,0,0}, a13={0,0,0,0};
    #pragma unroll
    for (int kk = 0; kk < 128; kk += 32) {
      half8_t f0 = *(const half8_t*)&P[lo][kk + grp*8];
      half8_t f1 = *(const half8_t*)&P[16 + lo][kk + grp*8];
      half8_t b0 = *(const half8_t*)(bp + kk);
      half8_t b1 = *(const half8_t*)(bp + kk + (size_t)16*128);
      half8_t b2 = *(const half8_t*)(bp + kk + (size_t)32*128);
      half8_t b3 = *(const half8_t*)(bp + kk + (size_t)48*128);
      a00 = MFMA32(f0, b0, a00);  a01 = MFMA32(f0, b1, a01);
      a02 = MFMA32(f0, b2, a02);  a03 = MFMA32(f0, b3, a03);
      a10 = MFMA32(f1, b0, a10);  a11 = MFMA32(f1, b1, a11);
      a12 = MFMA32(f1, b2, a12);  a13 = MFMA32(f1, b3, a13);
    }
    int colb = wid*64 + lo;
    #pragma unroll
    for (int r = 0; r < 4; ++r) {
      float vv[8] = { a00[r], a01[r], a02[r], a03[r], a10[r], a11[r], a12[r], a13[r] };
      #pragma unroll
      for (int j = 0; j < 8; ++j) {
        int rr  = grp*4 + r + (j >= 4 ? 16 : 0);
        int col = colb + (j & 3)*16;
        float v = vv[j] + fc1_b[col];
        float g = 0.5f * v * (1.0f + erff(v * 0.70710678118654752f));
        H[rr][col] = (_Float16)g;
      }
    }
  }
  __syncthreads();
  // phase 4: FC2 GEMM from H, wave -> 16-col stripe; +bias +X2 residual -> out
  {
    const _Float16* bp = fc2_wT + (size_t)(wid*16 + lo)*512 + grp*8;
    float4_t c0={0,0,0,0}, c1={0,0,0,0};
    #pragma unroll
    for (int kk = 0; kk < 512; kk += 32) {
      half8_t f0 = *(const half8_t*)&H[lo][kk + grp*8];
      half8_t f1 = *(const half8_t*)&H[16 + lo][kk + grp*8];
      half8_t b0 = *(const half8_t*)(bp + kk);
      c0 = MFMA32(f0, b0, c0);
      c1 = MFMA32(f1, b0, c1);
    }
    int colb = wid*16 + lo;
    float bb = fc2_b[colb];
    #pragma unroll
    for (int r = 0; r < 4; ++r) {
      int r0 = grp*4 + r;
      int row0 = mt*32 + r0;
      out[(size_t)row0*128 + colb]      = (float)X2[r0][colb]    + c0[r] + bb;
      out[(size_t)(row0+16)*128 + colb] = (float)X2[r0+16][colb] + c1[r] + bb;
    }
  }
}

extern "C" void kernel_launch(void* const* d_in, const int* in_sizes, int n_in,
                              void* d_out, int out_size, void* d_ws, size_t ws_size,
                              hipStream_t stream)
{
  const float* x      = (const float*)d_in[0];
  // d_in[1] mask_matrix, d_in[15] rel_index: reproduced analytically in-kernel
  const float* g1     = (const float*)d_in[2];
  const float* b1     = (const float*)d_in[3];
  const float* qkv_w  = (const float*)d_in[4];
  const float* qkv_b  = (const float*)d_in[5];
  const float* rpb    = (const float*)d_in[6];
  const float* proj_w = (const float*)d_in[7];
  const float* proj_b = (const float*)d_in[8];
  const float* g2     = (const float*)d_in[9];
  const float* b2     = (const float*)d_in[10];
  const float* fc1_w  = (const float*)d_in[11];
  const float* fc1_b  = (const float*)d_in[12];
  const float* fc2_w  = (const float*)d_in[13];
  const float* fc2_b  = (const float*)d_in[14];
  char* ws = (char*)d_ws;
  size_t o = 0;
  auto alloc = [&](size_t bytes) { size_t r = o; o += (bytes + 255) & ~size_t(255); return r; };
  size_t oOB  = alloc((size_t)NTOK*128*2);  // obuf (attn out, token order)
  size_t oU   = alloc((size_t)NTOK*512*2);  // qkvb
  size_t oWQ  = alloc(49152*2);
  size_t oWP  = alloc(16384*2);
  size_t oW1  = alloc(65536*2);
  size_t oW2  = alloc(65536*2);
  size_t oBT  = alloc((size_t)8*343*352*2); // bias table f16 (log2 domain)
  size_t oBM  = alloc((size_t)8*343*11*4);  // mask bitmasks
  (void)ws_size; (void)in_sizes; (void)n_in; (void)out_size;
  _Float16* obuf   = (_Float16*)(ws + oOB);
  _Float16* qkvb   = (_Float16*)(ws + oU);
  _Float16* qkv_wT = (_Float16*)(ws + oWQ);
  _Float16* proj_wT= (_Float16*)(ws + oWP);
  _Float16* fc1_wT = (_Float16*)(ws + oW1);
  _Float16* fc2_wT = (_Float16*)(ws + oW2);
  _Float16* biasT  = (_Float16*)(ws + oBT);
  unsigned* bmask  = (unsigned*)(ws + oBM);
  float*    out    = (float*)d_out;

  k_precomp<<<4662, 256, 0, stream>>>(qkv_w, proj_w, fc1_w, fc2_w, rpb,
                                      qkv_wT, proj_wT, fc1_wT, fc2_wT, biasT, bmask);
  k_qkv<<<686, 384, 0, stream>>>(x, g1, b1, qkv_wT, qkv_b, qkvb);
  k_attn<<<512, 512, 0, stream>>>(qkvb, biasT, bmask, obuf);
  k_mlp<<<686, 512, 0, stream>>>(obuf, proj_wT, proj_b, x, g2, b2,
                                 fc1_wT, fc1_b, fc2_wT, fc2_b, out);
}